// Round 9
// baseline (111.909 us; speedup 1.0000x reference)
//
#include <hip/hip_runtime.h>
#include <hip/hip_bf16.h>

#define BB 16
#define CC 512
#define HH 8
#define DD 64
#define NN 1024

using f32x4  = __attribute__((ext_vector_type(4))) float;
typedef __bf16 bf16x8 __attribute__((ext_vector_type(8)));
typedef __bf16 bf16x4 __attribute__((ext_vector_type(4)));

#define MFMA16(a, b, c) __builtin_amdgcn_mfma_f32_16x16x32_bf16((a), (b), (c), 0, 0, 0)

#define WAITVM8  asm volatile("s_waitcnt vmcnt(8)" ::: "memory")
#define WAITVM4  asm volatile("s_waitcnt vmcnt(4)" ::: "memory")
#define WAITVM0  asm volatile("s_waitcnt vmcnt(0)" ::: "memory")
#define BARRIER __builtin_amdgcn_s_barrier()
#define SCHEDB  __builtin_amdgcn_sched_barrier(0)

// async global->LDS, 16B per lane. LDS dest must be wave-uniform base (+lane*16);
// the GLOBAL source address is per-lane (enables pre-swizzled staging).
__device__ __forceinline__ void glds16(const __hip_bfloat16* g, __hip_bfloat16* l) {
  typedef __attribute__((address_space(1))) const void gv_t;
  typedef __attribute__((address_space(3))) void lv_t;
  __builtin_amdgcn_global_load_lds((gv_t*)g, (lv_t*)l, 16, 0, 0);
}

// -------------------------- prep: x transpose->bf16 (blocks 0..2047) + 4 weight
// cvts (blocks 2048..3071). x-tile branch ALSO writes xbf, a bf16 [b][c][n] copy
// of x — gemm_o's residual reads 16MB bf16 instead of 64MB fp32.
__global__ __launch_bounds__(256) void k_prep(
    const float* __restrict__ x, __hip_bfloat16* __restrict__ xT,
    __hip_bfloat16* __restrict__ xbf,
    const float* __restrict__ wq, const float* __restrict__ wk,
    const float* __restrict__ wv, const float* __restrict__ wo,
    __hip_bfloat16* __restrict__ wqb) {
  __shared__ float tile[64][65];
  const int L = blockIdx.x;
  const int t = threadIdx.x;
  if (L >= 2048) {
    const int j = L - 2048;
    const int mat = j >> 8;
    const float* s = (mat == 0) ? wq : (mat == 1) ? wk : (mat == 2) ? wv : wo;
    __hip_bfloat16* o = wqb + (size_t)mat * CC * CC;
    const int i = ((j & 255) * 256 + t) * 4;
    float4 v = *(const float4*)(s + i);
    alignas(8) __hip_bfloat16 tm[4];
    tm[0] = __float2bfloat16(v.x);
    tm[1] = __float2bfloat16(v.y);
    tm[2] = __float2bfloat16(v.z);
    tm[3] = __float2bfloat16(v.w);
    *(bf16x4*)(o + i) = *(const bf16x4*)tm;
    return;
  }
  const int c = L & 7, r = L >> 3;
  const int b  = c * 2 + (r >> 7);
  const int rr = r & 127;
  const int bn = (rr & 15) * 64;
  const int bc = (rr >> 4) * 64;

  const float* xb = x + ((size_t)b * CC + bc) * NN + bn;
  __hip_bfloat16* xbo = xbf + ((size_t)b * CC + bc) * NN + bn;
  const int r0 = t >> 4;
  const int c0 = (t & 15) * 4;
  for (int p = 0; p < 4; ++p) {
    const int rw = r0 + p * 16;
    float4 v = *(const float4*)(xb + (size_t)rw * NN + c0);
    tile[rw][c0 + 0] = v.x;
    tile[rw][c0 + 1] = v.y;
    tile[rw][c0 + 2] = v.z;
    tile[rw][c0 + 3] = v.w;
    alignas(8) __hip_bfloat16 tm[4];
    tm[0] = __float2bfloat16(v.x);
    tm[1] = __float2bfloat16(v.y);
    tm[2] = __float2bfloat16(v.z);
    tm[3] = __float2bfloat16(v.w);
    *(bf16x4*)(xbo + (size_t)rw * NN + c0) = *(const bf16x4*)tm;
  }
  __syncthreads();

  __hip_bfloat16* xo = xT + ((size_t)b * NN + bn) * CC + bc;
  const int rn0 = t >> 3;
  const int cc0 = (t & 7) * 8;
  for (int p = 0; p < 2; ++p) {
    const int rn = rn0 + p * 32;
    alignas(16) __hip_bfloat16 tmp[8];
    for (int j = 0; j < 8; ++j) tmp[j] = __float2bfloat16(tile[cc0 + j][rn]);
    *(bf16x8*)(xo + (size_t)rn * CC + cc0) = *(const bf16x8*)tmp;
  }
}

// ------------------------------------------ fused QKV GEMM (W rows 0..1535 = q,k,v)
// Round-23: single-buffer PERSISTENT. r8 evidence: occupancy up (30%) but 6
// block-generations of partial-line epilogues amplified WRITE 49.5->77.6MB.
// r4 evidence: persistence keeps WRITE at 49.5 but only 2 blk/CU. Combine:
// single 32KB buffer (3 blk/CU: LDS 96/160, VGPR 64), grid 768 = 128 bx x 6 by0,
// ALL co-resident, flat 16-K-tile loop = 2 output tiles (by = by0 + 6*rep).
// One fill, one epilogue generation, warm-L2 X restage, 3-way TLP. kt=8's VM0
// incidentally drains rep-0 stores (issued a stage-latency earlier — marginal).
// No inter-block sync: correct regardless of residency.
__global__ __launch_bounds__(256, 4) void k_gemm_qkv(
    const __hip_bfloat16* __restrict__ Wqkv,
    const __hip_bfloat16* __restrict__ Xt,
    const float* __restrict__ bq, const float* __restrict__ bk,
    const float* __restrict__ bv,
    __hip_bfloat16* __restrict__ qT, __hip_bfloat16* __restrict__ kT,
    __hip_bfloat16* __restrict__ vO, float qscale) {
  __shared__ __hip_bfloat16 Wl[8192];      // [128 rows][64 cols], single buffer
  __shared__ __hip_bfloat16 Xl[8192];
  const int bid = blockIdx.x;               // 0..767
  const int by0 = bid >> 7;                 // 0..5  (rep r handles by0 + 6r)
  const int bx  = bid & 127;                // 0..127
  const int nt  = bx * 128;                 // global n = b*1024 + n
  const int bb  = nt >> 10;                 // batch (128-tiles never cross b)
  const int nb  = nt & 1023;
  const int t  = threadIdx.x;
  const int w  = t >> 6, l = t & 63;
  const int wr = w >> 1, wc = w & 1;
  const int lg = l >> 4, lr16 = l & 15;

  f32x4 acc[4][4] = {};

  const int srow = w * 8 + (l >> 3);
  const int scol = ((l & 7) ^ ((l >> 3) & 7)) * 8;   // pre-swizzled global col
  const __hip_bfloat16* wsrc0 = Wqkv + (size_t)(by0 * 128 + srow) * CC + scol;
  const __hip_bfloat16* xsrc  = Xt + ((size_t)nt + srow) * CC + scol;

  const int s7 = lr16 & 7;
  const int slot0 = ((lg) ^ s7) * 8;
  const int slot1 = ((4 + lg) ^ s7) * 8;
  const int rowA = (wr * 64 + lr16) * 64;
  const int rowB = (wc * 64 + lr16) * 64;

  for (int ktg = 0; ktg < 16; ++ktg) {
    const int rep = ktg >> 3;               // 0,1
    const int k0  = (ktg & 7) * 64;
    const __hip_bfloat16* ws = wsrc0 + (size_t)rep * 768 * CC;  // +6*128 rows
    // ---- stage this K-tile (8 loads/lane; single buffer)
#pragma unroll
    for (int i = 0; i < 4; ++i)
      glds16(ws + (size_t)(i * 32) * CC + k0, &Wl[(w * 8 + i * 32) * 64]);
#pragma unroll
    for (int i = 0; i < 4; ++i)
      glds16(xsrc + (size_t)(i * 32) * CC + k0, &Xl[(w * 8 + i * 32) * 64]);
    WAITVM0;                 // own loads done; barrier makes all waves' done
    BARRIER; SCHEDB;
    // ---- 32 MFMA on the staged tile
#pragma unroll
    for (int ks = 0; ks < 2; ++ks) {
      const int sl = ks ? slot1 : slot0;
      bf16x8 af[4], bfr[4];
#pragma unroll
      for (int mi = 0; mi < 4; ++mi) af[mi] = *(const bf16x8*)(Wl + rowA + mi * 1024 + sl);
#pragma unroll
      for (int nj = 0; nj < 4; ++nj) bfr[nj] = *(const bf16x8*)(Xl + rowB + nj * 1024 + sl);
      __builtin_amdgcn_s_setprio(1);
#pragma unroll
      for (int mi = 0; mi < 4; ++mi)
#pragma unroll
        for (int nj = 0; nj < 4; ++nj)
          acc[mi][nj] = MFMA16(af[mi], bfr[nj], acc[mi][nj]);
      __builtin_amdgcn_s_setprio(0);
    }
    BARRIER;                 // all reads done before next stage overwrites

    if ((ktg & 7) == 7) {    // end of one output tile: epilogue
      const int by = by0 + 6 * rep;         // 0..11
      const int sector = by >> 2;           // 0 Q, 1 K, 2 V
      const float* bias = (sector == 0) ? bq : (sector == 1) ? bk : bv;
      const float scale = (sector == 0) ? qscale : 1.0f;
      __hip_bfloat16* outT = (sector == 0) ? qT : kT;
#pragma unroll
      for (int mi = 0; mi < 4; ++mi) {
        const int og = by * 128 + wr * 64 + mi * 16 + lg * 4;
        const int o0 = og & 511;
#pragma unroll
        for (int nj = 0; nj < 4; ++nj) {
          const int n = nb + wc * 64 + nj * 16 + lr16;
          if (sector < 2) {
            alignas(8) __hip_bfloat16 tmp[4];
#pragma unroll
            for (int rj = 0; rj < 4; ++rj)
              tmp[rj] = __float2bfloat16((acc[mi][nj][rj] + bias[o0 + rj]) * scale);
            const int hh = o0 >> 6, d0 = o0 & 63;
            *(bf16x4*)(outT + (((size_t)(bb * HH + hh)) * NN + n) * DD + d0) =
                *(const bf16x4*)tmp;
          } else {
#pragma unroll
            for (int rj = 0; rj < 4; ++rj)
              vO[((size_t)bb * CC + o0 + rj) * NN + n] =
                  __float2bfloat16(acc[mi][nj][rj] + bias[o0 + rj]);
          }
        }
      }
      if (ktg < 15) {
#pragma unroll
        for (int mi = 0; mi < 4; ++mi)
#pragma unroll
          for (int nj = 0; nj < 4; ++nj)
            acc[mi][nj] = f32x4{0.f, 0.f, 0.f, 0.f};
      }
    }
  }
}

// --------------------------------------------- output projection + residual GEMM
// (r4 exact) B = attT; residual from xbf.
__global__ __launch_bounds__(256, 4) void k_gemm_o(
    const __hip_bfloat16* __restrict__ W,
    const __hip_bfloat16* __restrict__ Xt,
    const float* __restrict__ bias,
    const __hip_bfloat16* __restrict__ xbf,
    const float* __restrict__ gamma,
    float* __restrict__ y) {
  __shared__ __hip_bfloat16 Wl[2][4096];
  __shared__ __hip_bfloat16 Xl[2][4096];
  const int b  = blockIdx.z;
  const int ot = blockIdx.y * 128;
  const int nt = blockIdx.x * 128;
  const int t  = threadIdx.x;
  const int w  = t >> 6, l = t & 63;
  const int wr = w >> 1, wc = w & 1;
  const int lg = l >> 4, lr16 = l & 15;

  f32x4 acc[4][4] = {};

  const int srow = w * 16 + (l >> 2);
  const int scol = ((l & 3) ^ ((l >> 3) & 3)) * 8;
  const __hip_bfloat16* ws0 = W + (size_t)(ot + srow) * CC + scol;
  const __hip_bfloat16* xs0 = Xt + ((size_t)b * NN + nt + srow) * CC + scol;

  const int sx  = (lg ^ ((lr16 >> 1) & 3)) * 8;
  const int rdA = (wr * 64 + lr16) * 32 + sx;
  const int rdB = (wc * 64 + lr16) * 32 + sx;

#define STAGEO(bn, k0)                                        \
  do {                                                        \
    glds16(ws0 + (k0), &Wl[bn][w * 512]);                     \
    glds16(ws0 + (size_t)64 * CC + (k0), &Wl[bn][2048 + w * 512]); \
    glds16(xs0 + (k0), &Xl[bn][w * 512]);                     \
    glds16(xs0 + (size_t)64 * CC + (k0), &Xl[bn][2048 + w * 512]); \
  } while (0)

  STAGEO(0, 0);
  for (int kt = 0; kt < 16; ++kt) {
    WAITVM0;
    BARRIER; SCHEDB;
    if (kt < 15) STAGEO((kt + 1) & 1, (kt + 1) * 32);
    const __hip_bfloat16* Wb = &Wl[kt & 1][0];
    const __hip_bfloat16* Xb = &Xl[kt & 1][0];
    bf16x8 af[4], bfr[4];
#pragma unroll
    for (int mi = 0; mi < 4; ++mi) af[mi] = *(const bf16x8*)(Wb + rdA + mi * 512);
#pragma unroll
    for (int nj = 0; nj < 4; ++nj) bfr[nj] = *(const bf16x8*)(Xb + rdB + nj * 512);
    __builtin_amdgcn_s_setprio(1);
#pragma unroll
    for (int mi = 0; mi < 4; ++mi)
#pragma unroll
      for (int nj = 0; nj < 4; ++nj)
        acc[mi][nj] = MFMA16(af[mi], bfr[nj], acc[mi][nj]);
    __builtin_amdgcn_s_setprio(0);
  }
#undef STAGEO

  const float g = gamma[0];
  for (int mi = 0; mi < 4; ++mi) {
    const int o0 = ot + wr * 64 + mi * 16 + lg * 4;
    for (int nj = 0; nj < 4; ++nj) {
      const int n = nt + wc * 64 + nj * 16 + lr16;
      for (int rj = 0; rj < 4; ++rj) {
        const size_t idx = ((size_t)b * CC + o0 + rj) * NN + n;
        y[idx] = g * (acc[mi][nj][rj] + bias[o0 + rj]) + __bfloat162float(xbf[idx]);
      }
    }
  }
}

// ---------------------------------------------------------------- attention core
// (r7 exact) T15 software pipeline: carry pf across iterations; QK^T[t+1] ->
// PV[t] -> EXP[t+1] per iter. qblk 256, 2 blk/CU, 3-buffer, VM4 ladder.
__global__ __launch_bounds__(256, 2) void k_attn(
    const __hip_bfloat16* __restrict__ qT,
    const __hip_bfloat16* __restrict__ kT,
    const __hip_bfloat16* __restrict__ v,
    __hip_bfloat16* __restrict__ attT) {
  __shared__ __hip_bfloat16 Kl[3][4096];
  __shared__ __hip_bfloat16 Vl[3][4096];

  const int L = blockIdx.x;                 // 512 blocks
  const int c = L & 7, s = L >> 3;
  const int bh = c * 16 + (s >> 2);
  const int i0 = (s & 3) * 256;
  const int b = bh >> 3, h = bh & 7;
  const int t  = threadIdx.x;
  const int w  = t >> 6, l = t & 63;
  const int lg = l >> 4, lr = l & 15;

  const __hip_bfloat16* qb = qT + ((size_t)(b * HH + h)) * NN * DD;
  const __hip_bfloat16* kb = kT + ((size_t)(b * HH + h)) * NN * DD;
  const __hip_bfloat16* vb = v + ((size_t)b * CC + h * DD) * NN;

  bf16x8 qf[4][2];
#pragma unroll
  for (int g = 0; g < 4; ++g) {
    const __hip_bfloat16* qp = qb + (size_t)(i0 + w * 64 + g * 16 + lr) * DD + lg * 8;
    qf[g][0] = *(const bf16x8*)qp;
    qf[g][1] = *(const bf16x8*)(qp + 32);
  }

  const int rA = w * 8 + (l >> 3);
  const int rB = rA + 32;
  const int sA = (l & 7) ^ ((rA & 3) ^ (((rA >> 3) & 1) << 2));
  const __hip_bfloat16* gKA = kb + rA * DD + sA * 8;
  const __hip_bfloat16* gKB = kb + rB * DD + sA * 8;
  const __hip_bfloat16* gVA = vb + (size_t)rA * NN + sA * 8;
  const __hip_bfloat16* gVB = vb + (size_t)rB * NN + sA * 8;

  auto STAGE = [&](int bufn, int tile) {
    glds16(gKA + (size_t)tile * 4096, &Kl[bufn][w * 512]);
    glds16(gKB + (size_t)tile * 4096, &Kl[bufn][2048 + w * 512]);
    glds16(gVA + tile * 64, &Vl[bufn][w * 512]);
    glds16(gVB + tile * 64, &Vl[bufn][2048 + w * 512]);
  };

  const int swzK = (lr & 3) ^ (((lr >> 2) & 1) << 2);
  const int krl  = 8 * (lr >> 2) + (lr & 3);
  const int offK0 = krl * 64 + ((lg ^ swzK) * 8);
  const int offK1 = krl * 64 + (((lg + 4) ^ swzK) * 8);
  const int swzV = (lr & 3) ^ (((lr >> 3) & 1) << 2);

  f32x4 accO[4][4] = {};
  f32x4 accL[4] = {};
  f32x4 st[4][4];
  bf16x8 pf[4][2];
  const bf16x8 ones = {(__bf16)1.f, (__bf16)1.f, (__bf16)1.f, (__bf16)1.f,
                       (__bf16)1.f, (__bf16)1.f, (__bf16)1.f, (__bf16)1.f};

  auto QK = [&](const __hip_bfloat16* Kb) {
    __builtin_amdgcn_s_setprio(1);
#pragma unroll
    for (int jt = 0; jt < 4; ++jt) {
      const int jo = (jt >> 1) * 2048 + (jt & 1) * 256;
      bf16x8 kf0 = *(const bf16x8*)(Kb + jo + offK0);
      bf16x8 kf1 = *(const bf16x8*)(Kb + jo + offK1);
#pragma unroll
      for (int g = 0; g < 4; ++g) {
        f32x4 a = {};
        a = MFMA16(kf0, qf[g][0], a);
        a = MFMA16(kf1, qf[g][1], a);
        st[g][jt] = a;
      }
    }
    __builtin_amdgcn_s_setprio(0);
  };

  auto EXP = [&]() {
#pragma unroll
    for (int g = 0; g < 4; ++g) {
      union { bf16x8 v8; __hip_bfloat16 h[8]; } pk0, pk1;
#pragma unroll
      for (int jt = 0; jt < 4; ++jt)
#pragma unroll
        for (int rj = 0; rj < 4; ++rj) {
          const float p = __builtin_amdgcn_exp2f(st[g][jt][rj]);
          if (jt < 2) pk0.h[(jt & 1) * 4 + rj] = __float2bfloat16(p);
          else        pk1.h[(jt & 1) * 4 + rj] = __float2bfloat16(p);
        }
      pf[g][0] = pk0.v8;
      pf[g][1] = pk1.v8;
    }
  };

  auto PV = [&](const __hip_bfloat16* Vb) {
    __builtin_amdgcn_s_setprio(1);
#pragma unroll
    for (int ks = 0; ks < 2; ++ks) {
#pragma unroll
      for (int dt = 0; dt < 4; ++dt) {
        bf16x8 vf = *(const bf16x8*)(Vb + (dt * 16 + lr) * 64 + (((ks * 4 + lg) ^ swzV) * 8));
#pragma unroll
        for (int g = 0; g < 4; ++g)
          accO[g][dt] = MFMA16(pf[g][ks], vf, accO[g][dt]);
      }
#pragma unroll
      for (int g = 0; g < 4; ++g)
        accL[g] = MFMA16(pf[g][ks], ones, accL[g]);
    }
    __builtin_amdgcn_s_setprio(0);
  };

  STAGE(0, 0);
  STAGE(1, 1);
  STAGE(2, 2);
  WAITVM8;                 // tile0 complete (tiles 1,2 = 8 loads in flight)
  BARRIER;
  QK(&Kl[0][0]);           // st = scores(tile0)
  EXP();                   // pf = P(tile0)

  for (int tl = 0; tl < 16; ++tl) {
    const int cur = tl % 3;
    if (tl < 15) {
      if (tl < 14) { WAITVM4; } else { WAITVM0; }
      BARRIER; SCHEDB;
      QK(&Kl[(tl + 1) % 3][0]);   // st = scores(tl+1), indep of pf
      PV(&Vl[cur][0]);            // consumes pf = P(tl)
      EXP();                      // pf = P(tl+1); VALU overlaps PV drain
      BARRIER;
      if (tl < 13) STAGE(cur, tl + 3);
    } else {
      PV(&Vl[cur][0]);            // final tile
    }
  }

#pragma unroll
  for (int g = 0; g < 4; ++g)
#pragma unroll
    for (int dt = 0; dt < 4; ++dt) {
      f32x4 o;
#pragma unroll
      for (int rj = 0; rj < 4; ++rj) o[rj] = accO[g][dt][rj] / accL[g][rj];
#pragma unroll
      for (int rj = 0; rj < 4; ++rj) {
        const int i = i0 + w * 64 + g * 16 + 4 * lg + rj;
        const int d = dt * 16 + lr;
        attT[((size_t)b * NN + i) * CC + h * DD + d] = __float2bfloat16(o[rj]);
      }
    }
}

// ----------------------------------------------------------------------------
extern "C" void kernel_launch(void* const* d_in, const int* in_sizes, int n_in,
                              void* d_out, int out_size, void* d_ws, size_t ws_size,
                              hipStream_t stream) {
  const float* x     = (const float*)d_in[0];
  const float* wq    = (const float*)d_in[1];
  const float* bq    = (const float*)d_in[2];
  const float* wk    = (const float*)d_in[3];
  const float* bk    = (const float*)d_in[4];
  const float* wv    = (const float*)d_in[5];
  const float* bv    = (const float*)d_in[6];
  const float* wo    = (const float*)d_in[7];
  const float* bo    = (const float*)d_in[8];
  const float* gamma = (const float*)d_in[9];
  float* y = (float*)d_out;

  char* ws = (char*)d_ws;
  const size_t szT = (size_t)BB * NN * CC * 2;
  __hip_bfloat16* xT  = (__hip_bfloat16*)(ws);            // attn overwrites as attT
  __hip_bfloat16* qT  = (__hip_bfloat16*)(ws + szT);
  __hip_bfloat16* kTb = (__hip_bfloat16*)(ws + 2 * szT);
  __hip_bfloat16* vB  = (__hip_bfloat16*)(ws + 3 * szT);
  __hip_bfloat16* xbf = (__hip_bfloat16*)(ws + 4 * szT);  // bf16 [b][c][n] copy of x
  __hip_bfloat16* wqb = (__hip_bfloat16*)(ws + 5 * szT);  // wq,wk,wv,wo contiguous
  __hip_bfloat16* wob = wqb + (size_t)3 * CC * CC;

  k_prep<<<dim3(2048 + 1024), 256, 0, stream>>>(x, xT, xbf, wq, wk, wv, wo, wqb);

  // Q pre-scaled by SCALE * log2(e) so attention uses exp2 directly.
  const float qsc = 0.125f * 1.44269504f;
  k_gemm_qkv<<<dim3(768), 256, 0, stream>>>(
      wqb, xT, bq, bk, bv, qT, kTb, vB, qsc);

  // attn writes attT over the (now dead) xT buffer
  k_attn<<<dim3(BB * HH * (NN / 256)), 256, 0, stream>>>(qT, kTb, vB, xT);

  k_gemm_o<<<dim3(NN / 128, CC / 128, BB), 256, 0, stream>>>(
      wob, xT, bo, xbf, gamma, y);
}

// Round 10
// 109.092 us; speedup vs baseline: 1.0258x; 1.0258x over previous
//
#include <hip/hip_runtime.h>
#include <hip/hip_bf16.h>

#define BB 16
#define CC 512
#define HH 8
#define DD 64
#define NN 1024

using f32x4  = __attribute__((ext_vector_type(4))) float;
typedef __bf16 bf16x8 __attribute__((ext_vector_type(8)));
typedef __bf16 bf16x4 __attribute__((ext_vector_type(4)));

#define MFMA16(a, b, c) __builtin_amdgcn_mfma_f32_16x16x32_bf16((a), (b), (c), 0, 0, 0)

#define WAITVM16 asm volatile("s_waitcnt vmcnt(16)" ::: "memory")
#define WAITVM8  asm volatile("s_waitcnt vmcnt(8)" ::: "memory")
#define WAITVM4  asm volatile("s_waitcnt vmcnt(4)" ::: "memory")
#define WAITVM0  asm volatile("s_waitcnt vmcnt(0)" ::: "memory")
#define BARRIER __builtin_amdgcn_s_barrier()
#define SCHEDB  __builtin_amdgcn_sched_barrier(0)

// async global->LDS, 16B per lane. LDS dest must be wave-uniform base (+lane*16);
// the GLOBAL source address is per-lane (enables pre-swizzled staging).
__device__ __forceinline__ void glds16(const __hip_bfloat16* g, __hip_bfloat16* l) {
  typedef __attribute__((address_space(1))) const void gv_t;
  typedef __attribute__((address_space(3))) void lv_t;
  __builtin_amdgcn_global_load_lds((gv_t*)g, (lv_t*)l, 16, 0, 0);
}

// -------------------------- prep: x transpose->bf16 (blocks 0..2047) + 4 weight
// cvts (blocks 2048..3071). x-tile branch ALSO writes xbf, a bf16 [b][c][n] copy
// of x — gemm_o's residual reads 16MB bf16 instead of 64MB fp32.
__global__ __launch_bounds__(256) void k_prep(
    const float* __restrict__ x, __hip_bfloat16* __restrict__ xT,
    __hip_bfloat16* __restrict__ xbf,
    const float* __restrict__ wq, const float* __restrict__ wk,
    const float* __restrict__ wv, const float* __restrict__ wo,
    __hip_bfloat16* __restrict__ wqb) {
  __shared__ float tile[64][65];
  const int L = blockIdx.x;
  const int t = threadIdx.x;
  if (L >= 2048) {
    const int j = L - 2048;
    const int mat = j >> 8;
    const float* s = (mat == 0) ? wq : (mat == 1) ? wk : (mat == 2) ? wv : wo;
    __hip_bfloat16* o = wqb + (size_t)mat * CC * CC;
    const int i = ((j & 255) * 256 + t) * 4;
    float4 v = *(const float4*)(s + i);
    alignas(8) __hip_bfloat16 tm[4];
    tm[0] = __float2bfloat16(v.x);
    tm[1] = __float2bfloat16(v.y);
    tm[2] = __float2bfloat16(v.z);
    tm[3] = __float2bfloat16(v.w);
    *(bf16x4*)(o + i) = *(const bf16x4*)tm;
    return;
  }
  const int c = L & 7, r = L >> 3;
  const int b  = c * 2 + (r >> 7);
  const int rr = r & 127;
  const int bn = (rr & 15) * 64;
  const int bc = (rr >> 4) * 64;

  const float* xb = x + ((size_t)b * CC + bc) * NN + bn;
  __hip_bfloat16* xbo = xbf + ((size_t)b * CC + bc) * NN + bn;
  const int r0 = t >> 4;
  const int c0 = (t & 15) * 4;
  for (int p = 0; p < 4; ++p) {
    const int rw = r0 + p * 16;
    float4 v = *(const float4*)(xb + (size_t)rw * NN + c0);
    tile[rw][c0 + 0] = v.x;
    tile[rw][c0 + 1] = v.y;
    tile[rw][c0 + 2] = v.z;
    tile[rw][c0 + 3] = v.w;
    alignas(8) __hip_bfloat16 tm[4];
    tm[0] = __float2bfloat16(v.x);
    tm[1] = __float2bfloat16(v.y);
    tm[2] = __float2bfloat16(v.z);
    tm[3] = __float2bfloat16(v.w);
    *(bf16x4*)(xbo + (size_t)rw * NN + c0) = *(const bf16x4*)tm;
  }
  __syncthreads();

  __hip_bfloat16* xo = xT + ((size_t)b * NN + bn) * CC + bc;
  const int rn0 = t >> 3;
  const int cc0 = (t & 7) * 8;
  for (int p = 0; p < 2; ++p) {
    const int rn = rn0 + p * 32;
    alignas(16) __hip_bfloat16 tmp[8];
    for (int j = 0; j < 8; ++j) tmp[j] = __float2bfloat16(tile[cc0 + j][rn]);
    *(bf16x8*)(xo + (size_t)rn * CC + cc0) = *(const bf16x8*)tmp;
  }
}

// ------------------------------------------ fused QKV GEMM (W rows 0..1535 = q,k,v)
// r4-persistent engine (measured best: 42.7us, WRITE at ideal 49.5MB). PLATEAU
// DECLARED (r9): 7 structures all land 585-607 TF = the m233 2-phase ceiling;
// occupancy/persistence/phase variants move counters (FETCH, delivery, WRITE)
// but not time. Do not touch. 512 blocks (2/CU), flat 24-K-tile loop = 3 output
// tiles (Q,K,V); vmcnt ladder kt%8==0 -> vmcnt(16), else vmcnt(8), kt=23 -> 0.
__global__ __launch_bounds__(256, 2) void k_gemm_qkv(
    const __hip_bfloat16* __restrict__ Wqkv,
    const __hip_bfloat16* __restrict__ Xt,
    const float* __restrict__ bq, const float* __restrict__ bk,
    const float* __restrict__ bv,
    __hip_bfloat16* __restrict__ qT, __hip_bfloat16* __restrict__ kT,
    __hip_bfloat16* __restrict__ vO, float qscale) {
  __shared__ __hip_bfloat16 Wl[2][8192];   // [128 rows][64 cols] per buffer
  __shared__ __hip_bfloat16 Xl[2][8192];
  const int bid = blockIdx.x;               // 0..511
  const int by0 = bid >> 7;                 // 0..3   (rep r handles by0 + 4r)
  const int bx  = bid & 127;                // 0..127
  const int nt  = bx * 128;                 // global n = b*1024 + n
  const int bb  = nt >> 10;                 // batch (128-tiles never cross b)
  const int nb  = nt & 1023;
  const int t  = threadIdx.x;
  const int w  = t >> 6, l = t & 63;
  const int wr = w >> 1, wc = w & 1;
  const int lg = l >> 4, lr16 = l & 15;

  f32x4 acc[4][4] = {};

  const int srow = w * 8 + (l >> 3);
  const int scol = ((l & 7) ^ ((l >> 3) & 7)) * 8;   // pre-swizzled global col
  const __hip_bfloat16* wsrc0 = Wqkv + (size_t)(by0 * 128 + srow) * CC + scol;
  const __hip_bfloat16* xsrc  = Xt + ((size_t)nt + srow) * CC + scol;

  // 8 loads/lane per K-tile; A source re-based per rep (+512 rows per rep)
  auto STAGE = [&](int bn, int ktg) {
    const int rep = ktg >> 3;
    const int k0  = (ktg & 7) * 64;
    const __hip_bfloat16* ws = wsrc0 + (size_t)rep * 512 * CC;
#pragma unroll
    for (int i = 0; i < 4; ++i)
      glds16(ws + (size_t)(i * 32) * CC + k0, &Wl[bn][(w * 8 + i * 32) * 64]);
#pragma unroll
    for (int i = 0; i < 4; ++i)
      glds16(xsrc + (size_t)(i * 32) * CC + k0, &Xl[bn][(w * 8 + i * 32) * 64]);
  };

  const int s7 = lr16 & 7;
  const int slot0 = ((lg) ^ s7) * 8;
  const int slot1 = ((4 + lg) ^ s7) * 8;
  const int rowA = (wr * 64 + lr16) * 64;
  const int rowB = (wc * 64 + lr16) * 64;

  auto STEP = [&](int bn) {
    const __hip_bfloat16* Wb = &Wl[bn][0];
    const __hip_bfloat16* Xb = &Xl[bn][0];
#pragma unroll
    for (int ks = 0; ks < 2; ++ks) {
      const int sl = ks ? slot1 : slot0;
      bf16x8 af[4], bfr[4];
#pragma unroll
      for (int mi = 0; mi < 4; ++mi) af[mi] = *(const bf16x8*)(Wb + rowA + mi * 1024 + sl);
#pragma unroll
      for (int nj = 0; nj < 4; ++nj) bfr[nj] = *(const bf16x8*)(Xb + rowB + nj * 1024 + sl);
      __builtin_amdgcn_s_setprio(1);
#pragma unroll
      for (int mi = 0; mi < 4; ++mi)
#pragma unroll
        for (int nj = 0; nj < 4; ++nj)
          acc[mi][nj] = MFMA16(af[mi], bfr[nj], acc[mi][nj]);
      __builtin_amdgcn_s_setprio(0);
    }
  };

  STAGE(0, 0);
  STAGE(1, 1);
  for (int ktg = 0; ktg < 24; ++ktg) {
    if (ktg == 23)                    { WAITVM0;  }
    else if (ktg > 0 && (ktg & 7) == 0) { WAITVM16; }  // don't force store drain
    else                              { WAITVM8;  }
    BARRIER; SCHEDB;
    STEP(ktg & 1);
    BARRIER;
    if (ktg < 22) STAGE(ktg & 1, ktg + 2);

    if ((ktg & 7) == 7) {             // end of one output tile: epilogue
      const int rep = ktg >> 3;       // 0 Q, 1 K, 2 V
      const float* bias = (rep == 0) ? bq : (rep == 1) ? bk : bv;
      const float scale = (rep == 0) ? qscale : 1.0f;
      __hip_bfloat16* outT = (rep == 0) ? qT : kT;
#pragma unroll
      for (int mi = 0; mi < 4; ++mi) {
        const int o0 = by0 * 128 + wr * 64 + mi * 16 + lg * 4;   // 0..511
#pragma unroll
        for (int nj = 0; nj < 4; ++nj) {
          const int n = nb + wc * 64 + nj * 16 + lr16;
          if (rep < 2) {
            alignas(8) __hip_bfloat16 tmp[4];
#pragma unroll
            for (int rj = 0; rj < 4; ++rj)
              tmp[rj] = __float2bfloat16((acc[mi][nj][rj] + bias[o0 + rj]) * scale);
            const int hh = o0 >> 6, d0 = o0 & 63;
            *(bf16x4*)(outT + (((size_t)(bb * HH + hh)) * NN + n) * DD + d0) =
                *(const bf16x4*)tmp;
          } else {
#pragma unroll
            for (int rj = 0; rj < 4; ++rj)
              vO[((size_t)bb * CC + o0 + rj) * NN + n] =
                  __float2bfloat16(acc[mi][nj][rj] + bias[o0 + rj]);
          }
        }
      }
      if (ktg < 23) {
#pragma unroll
        for (int mi = 0; mi < 4; ++mi)
#pragma unroll
          for (int nj = 0; nj < 4; ++nj)
            acc[mi][nj] = f32x4{0.f, 0.f, 0.f, 0.f};
      }
    }
  }
}

// --------------------------------------------- output projection + residual GEMM
// Round-24: the last uncleaned schedule — 16 full vmcnt(0) drains/block. Clean
// version of r6's fix WITHOUT its poison pills (nt stores, (256,2)): 3-buffer
// (24KB LDS; (256,4) keeps >=4 blk/CU: 160/24=6 LDS-wise), counted WAITVM4
// ladder, stage kt+2 after compute. WAR-safe: buffer staged at kt was last read
// at kt-1 (one barrier earlier); reads of kt's buffer complete before the next
// iteration's barrier (lgkm-waited by compiler before MFMA use).
// Normal stores for y; residual from xbf.
__global__ __launch_bounds__(256, 4) void k_gemm_o(
    const __hip_bfloat16* __restrict__ W,
    const __hip_bfloat16* __restrict__ Xt,
    const float* __restrict__ bias,
    const __hip_bfloat16* __restrict__ xbf,
    const float* __restrict__ gamma,
    float* __restrict__ y) {
  __shared__ __hip_bfloat16 Wl[3][4096];
  __shared__ __hip_bfloat16 Xl[3][4096];
  const int b  = blockIdx.z;
  const int ot = blockIdx.y * 128;
  const int nt = blockIdx.x * 128;
  const int t  = threadIdx.x;
  const int w  = t >> 6, l = t & 63;
  const int wr = w >> 1, wc = w & 1;
  const int lg = l >> 4, lr16 = l & 15;

  f32x4 acc[4][4] = {};

  const int srow = w * 16 + (l >> 2);
  const int scol = ((l & 3) ^ ((l >> 3) & 3)) * 8;
  const __hip_bfloat16* ws0 = W + (size_t)(ot + srow) * CC + scol;
  const __hip_bfloat16* xs0 = Xt + ((size_t)b * NN + nt + srow) * CC + scol;

  const int sx  = (lg ^ ((lr16 >> 1) & 3)) * 8;
  const int rdA = (wr * 64 + lr16) * 32 + sx;
  const int rdB = (wc * 64 + lr16) * 32 + sx;

#define STAGEO(bn, k0)                                        \
  do {                                                        \
    glds16(ws0 + (k0), &Wl[bn][w * 512]);                     \
    glds16(ws0 + (size_t)64 * CC + (k0), &Wl[bn][2048 + w * 512]); \
    glds16(xs0 + (k0), &Xl[bn][w * 512]);                     \
    glds16(xs0 + (size_t)64 * CC + (k0), &Xl[bn][2048 + w * 512]); \
  } while (0)

  STAGEO(0, 0);
  STAGEO(1, 32);
  for (int kt = 0; kt < 16; ++kt) {
    if (kt < 15) { WAITVM4; } else { WAITVM0; }
    BARRIER; SCHEDB;
    const __hip_bfloat16* Wb = &Wl[kt % 3][0];
    const __hip_bfloat16* Xb = &Xl[kt % 3][0];
    bf16x8 af[4], bfr[4];
#pragma unroll
    for (int mi = 0; mi < 4; ++mi) af[mi] = *(const bf16x8*)(Wb + rdA + mi * 512);
#pragma unroll
    for (int nj = 0; nj < 4; ++nj) bfr[nj] = *(const bf16x8*)(Xb + rdB + nj * 512);
    __builtin_amdgcn_s_setprio(1);
#pragma unroll
    for (int mi = 0; mi < 4; ++mi)
#pragma unroll
      for (int nj = 0; nj < 4; ++nj)
        acc[mi][nj] = MFMA16(af[mi], bfr[nj], acc[mi][nj]);
    __builtin_amdgcn_s_setprio(0);
    BARRIER;
    if (kt < 14) STAGEO((kt + 2) % 3, (kt + 2) * 32);
  }
#undef STAGEO

  const float g = gamma[0];
  for (int mi = 0; mi < 4; ++mi) {
    const int o0 = ot + wr * 64 + mi * 16 + lg * 4;
    for (int nj = 0; nj < 4; ++nj) {
      const int n = nt + wc * 64 + nj * 16 + lr16;
      for (int rj = 0; rj < 4; ++rj) {
        const size_t idx = ((size_t)b * CC + o0 + rj) * NN + n;
        y[idx] = g * (acc[mi][nj][rj] + bias[o0 + rj]) + __bfloat162float(xbf[idx]);
      }
    }
  }
}

// ---------------------------------------------------------------- attention core
// (r7 exact — best measured) T15 software pipeline: carry pf across iterations;
// QK^T[t+1] -> PV[t] -> EXP[t+1] per iter. qblk 256, 2 blk/CU (work-capped:
// only 512 q-blocks exist), 3-buffer, VM4 ladder.
__global__ __launch_bounds__(256, 2) void k_attn(
    const __hip_bfloat16* __restrict__ qT,
    const __hip_bfloat16* __restrict__ kT,
    const __hip_bfloat16* __restrict__ v,
    __hip_bfloat16* __restrict__ attT) {
  __shared__ __hip_bfloat16 Kl[3][4096];
  __shared__ __hip_bfloat16 Vl[3][4096];

  const int L = blockIdx.x;                 // 512 blocks
  const int c = L & 7, s = L >> 3;
  const int bh = c * 16 + (s >> 2);
  const int i0 = (s & 3) * 256;
  const int b = bh >> 3, h = bh & 7;
  const int t  = threadIdx.x;
  const int w  = t >> 6, l = t & 63;
  const int lg = l >> 4, lr = l & 15;

  const __hip_bfloat16* qb = qT + ((size_t)(b * HH + h)) * NN * DD;
  const __hip_bfloat16* kb = kT + ((size_t)(b * HH + h)) * NN * DD;
  const __hip_bfloat16* vb = v + ((size_t)b * CC + h * DD) * NN;

  bf16x8 qf[4][2];
#pragma unroll
  for (int g = 0; g < 4; ++g) {
    const __hip_bfloat16* qp = qb + (size_t)(i0 + w * 64 + g * 16 + lr) * DD + lg * 8;
    qf[g][0] = *(const bf16x8*)qp;
    qf[g][1] = *(const bf16x8*)(qp + 32);
  }

  const int rA = w * 8 + (l >> 3);
  const int rB = rA + 32;
  const int sA = (l & 7) ^ ((rA & 3) ^ (((rA >> 3) & 1) << 2));
  const __hip_bfloat16* gKA = kb + rA * DD + sA * 8;
  const __hip_bfloat16* gKB = kb + rB * DD + sA * 8;
  const __hip_bfloat16* gVA = vb + (size_t)rA * NN + sA * 8;
  const __hip_bfloat16* gVB = vb + (size_t)rB * NN + sA * 8;

  auto STAGE = [&](int bufn, int tile) {
    glds16(gKA + (size_t)tile * 4096, &Kl[bufn][w * 512]);
    glds16(gKB + (size_t)tile * 4096, &Kl[bufn][2048 + w * 512]);
    glds16(gVA + tile * 64, &Vl[bufn][w * 512]);
    glds16(gVB + tile * 64, &Vl[bufn][2048 + w * 512]);
  };

  const int swzK = (lr & 3) ^ (((lr >> 2) & 1) << 2);
  const int krl  = 8 * (lr >> 2) + (lr & 3);
  const int offK0 = krl * 64 + ((lg ^ swzK) * 8);
  const int offK1 = krl * 64 + (((lg + 4) ^ swzK) * 8);
  const int swzV = (lr & 3) ^ (((lr >> 3) & 1) << 2);

  f32x4 accO[4][4] = {};
  f32x4 accL[4] = {};
  f32x4 st[4][4];
  bf16x8 pf[4][2];
  const bf16x8 ones = {(__bf16)1.f, (__bf16)1.f, (__bf16)1.f, (__bf16)1.f,
                       (__bf16)1.f, (__bf16)1.f, (__bf16)1.f, (__bf16)1.f};

  auto QK = [&](const __hip_bfloat16* Kb) {
    __builtin_amdgcn_s_setprio(1);
#pragma unroll
    for (int jt = 0; jt < 4; ++jt) {
      const int jo = (jt >> 1) * 2048 + (jt & 1) * 256;
      bf16x8 kf0 = *(const bf16x8*)(Kb + jo + offK0);
      bf16x8 kf1 = *(const bf16x8*)(Kb + jo + offK1);
#pragma unroll
      for (int g = 0; g < 4; ++g) {
        f32x4 a = {};
        a = MFMA16(kf0, qf[g][0], a);
        a = MFMA16(kf1, qf[g][1], a);
        st[g][jt] = a;
      }
    }
    __builtin_amdgcn_s_setprio(0);
  };

  auto EXP = [&]() {
#pragma unroll
    for (int g = 0; g < 4; ++g) {
      union { bf16x8 v8; __hip_bfloat16 h[8]; } pk0, pk1;
#pragma unroll
      for (int jt = 0; jt < 4; ++jt)
#pragma unroll
        for (int rj = 0; rj < 4; ++rj) {
          const float p = __builtin_amdgcn_exp2f(st[g][jt][rj]);
          if (jt < 2) pk0.h[(jt & 1) * 4 + rj] = __float2bfloat16(p);
          else        pk1.h[(jt & 1) * 4 + rj] = __float2bfloat16(p);
        }
      pf[g][0] = pk0.v8;
      pf[g][1] = pk1.v8;
    }
  };

  auto PV = [&](const __hip_bfloat16* Vb) {
    __builtin_amdgcn_s_setprio(1);
#pragma unroll
    for (int ks = 0; ks < 2; ++ks) {
#pragma unroll
      for (int dt = 0; dt < 4; ++dt) {
        bf16x8 vf = *(const bf16x8*)(Vb + (dt * 16 + lr) * 64 + (((ks * 4 + lg) ^ swzV) * 8));
#pragma unroll
        for (int g = 0; g < 4; ++g)
          accO[g][dt] = MFMA16(pf[g][ks], vf, accO[g][dt]);
      }
#pragma unroll
      for (int g = 0; g < 4; ++g)
        accL[g] = MFMA16(pf[g][ks], ones, accL[g]);
    }
    __builtin_amdgcn_s_setprio(0);
  };

  STAGE(0, 0);
  STAGE(1, 1);
  STAGE(2, 2);
  WAITVM8;                 // tile0 complete (tiles 1,2 = 8 loads in flight)
  BARRIER;
  QK(&Kl[0][0]);           // st = scores(tile0)
  EXP();                   // pf = P(tile0)

  for (int tl = 0; tl < 16; ++tl) {
    const int cur = tl % 3;
    if (tl < 15) {
      if (tl < 14) { WAITVM4; } else { WAITVM0; }
      BARRIER; SCHEDB;
      QK(&Kl[(tl + 1) % 3][0]);   // st = scores(tl+1), indep of pf
      PV(&Vl[cur][0]);            // consumes pf = P(tl)
      EXP();                      // pf = P(tl+1); VALU overlaps PV drain
      BARRIER;
      if (tl < 13) STAGE(cur, tl + 3);
    } else {
      PV(&Vl[cur][0]);            // final tile
    }
  }

#pragma unroll
  for (int g = 0; g < 4; ++g)
#pragma unroll
    for (int dt = 0; dt < 4; ++dt) {
      f32x4 o;
#pragma unroll
      for (int rj = 0; rj < 4; ++rj) o[rj] = accO[g][dt][rj] / accL[g][rj];
#pragma unroll
      for (int rj = 0; rj < 4; ++rj) {
        const int i = i0 + w * 64 + g * 16 + 4 * lg + rj;
        const int d = dt * 16 + lr;
        attT[((size_t)b * NN + i) * CC + h * DD + d] = __float2bfloat16(o[rj]);
      }
    }
}

// ----------------------------------------------------------------------------
extern "C" void kernel_launch(void* const* d_in, const int* in_sizes, int n_in,
                              void* d_out, int out_size, void* d_ws, size_t ws_size,
                              hipStream_t stream) {
  const float* x     = (const float*)d_in[0];
  const float* wq    = (const float*)d_in[1];
  const float* bq    = (const float*)d_in[2];
  const float* wk    = (const float*)d_in[3];
  const float* bk    = (const float*)d_in[4];
  const float* wv    = (const float*)d_in[5];
  const float* bv    = (const float*)d_in[6];
  const float* wo    = (const float*)d_in[7];
  const float* bo    = (const float*)d_in[8];
  const float* gamma = (const float*)d_in[9];
  float* y = (float*)d_out;

  char* ws = (char*)d_ws;
  const size_t szT = (size_t)BB * NN * CC * 2;
  __hip_bfloat16* xT  = (__hip_bfloat16*)(ws);            // attn overwrites as attT
  __hip_bfloat16* qT  = (__hip_bfloat16*)(ws + szT);
  __hip_bfloat16* kTb = (__hip_bfloat16*)(ws + 2 * szT);
  __hip_bfloat16* vB  = (__hip_bfloat16*)(ws + 3 * szT);
  __hip_bfloat16* xbf = (__hip_bfloat16*)(ws + 4 * szT);  // bf16 [b][c][n] copy of x
  __hip_bfloat16* wqb = (__hip_bfloat16*)(ws + 5 * szT);  // wq,wk,wv,wo contiguous
  __hip_bfloat16* wob = wqb + (size_t)3 * CC * CC;

  k_prep<<<dim3(2048 + 1024), 256, 0, stream>>>(x, xT, xbf, wq, wk, wv, wo, wqb);

  // Q pre-scaled by SCALE * log2(e) so attention uses exp2 directly.
  const float qsc = 0.125f * 1.44269504f;
  k_gemm_qkv<<<dim3(512), 256, 0, stream>>>(
      wqb, xT, bq, bk, bv, qT, kTb, vB, qsc);

  // attn writes attT over the (now dead) xT buffer
  k_attn<<<dim3(BB * HH * (NN / 256)), 256, 0, stream>>>(qT, kTb, vB, xT);

  k_gemm_o<<<dim3(NN / 128, CC / 128, BB), 256, 0, stream>>>(
      wob, xT, bo, xbf, gamma, y);
}

// Round 11
// 108.351 us; speedup vs baseline: 1.0328x; 1.0068x over previous
//
#include <hip/hip_runtime.h>
#include <hip/hip_bf16.h>

#define BB 16
#define CC 512
#define HH 8
#define DD 64
#define NN 1024

using f32x4  = __attribute__((ext_vector_type(4))) float;
typedef __bf16 bf16x8 __attribute__((ext_vector_type(8)));
typedef __bf16 bf16x4 __attribute__((ext_vector_type(4)));

#define MFMA16(a, b, c) __builtin_amdgcn_mfma_f32_16x16x32_bf16((a), (b), (c), 0, 0, 0)

#define WAITVM16 asm volatile("s_waitcnt vmcnt(16)" ::: "memory")
#define WAITVM8  asm volatile("s_waitcnt vmcnt(8)" ::: "memory")
#define WAITVM4  asm volatile("s_waitcnt vmcnt(4)" ::: "memory")
#define WAITVM0  asm volatile("s_waitcnt vmcnt(0)" ::: "memory")
#define BARRIER __builtin_amdgcn_s_barrier()
#define SCHEDB  __builtin_amdgcn_sched_barrier(0)

// async global->LDS, 16B per lane. LDS dest must be wave-uniform base (+lane*16);
// the GLOBAL source address is per-lane (enables pre-swizzled staging).
__device__ __forceinline__ void glds16(const __hip_bfloat16* g, __hip_bfloat16* l) {
  typedef __attribute__((address_space(1))) const void gv_t;
  typedef __attribute__((address_space(3))) void lv_t;
  __builtin_amdgcn_global_load_lds((gv_t*)g, (lv_t*)l, 16, 0, 0);
}

// -------------------------- prep: x transpose->bf16 (blocks 0..2047) + 4 weight
// cvts (blocks 2048..3071). x-tile branch ALSO writes xbf, a bf16 [b][c][n] copy
// of x — gemm_o's residual reads 16MB bf16 instead of 64MB fp32.
__global__ __launch_bounds__(256) void k_prep(
    const float* __restrict__ x, __hip_bfloat16* __restrict__ xT,
    __hip_bfloat16* __restrict__ xbf,
    const float* __restrict__ wq, const float* __restrict__ wk,
    const float* __restrict__ wv, const float* __restrict__ wo,
    __hip_bfloat16* __restrict__ wqb) {
  __shared__ float tile[64][65];
  const int L = blockIdx.x;
  const int t = threadIdx.x;
  if (L >= 2048) {
    const int j = L - 2048;
    const int mat = j >> 8;
    const float* s = (mat == 0) ? wq : (mat == 1) ? wk : (mat == 2) ? wv : wo;
    __hip_bfloat16* o = wqb + (size_t)mat * CC * CC;
    const int i = ((j & 255) * 256 + t) * 4;
    float4 v = *(const float4*)(s + i);
    alignas(8) __hip_bfloat16 tm[4];
    tm[0] = __float2bfloat16(v.x);
    tm[1] = __float2bfloat16(v.y);
    tm[2] = __float2bfloat16(v.z);
    tm[3] = __float2bfloat16(v.w);
    *(bf16x4*)(o + i) = *(const bf16x4*)tm;
    return;
  }
  const int c = L & 7, r = L >> 3;
  const int b  = c * 2 + (r >> 7);
  const int rr = r & 127;
  const int bn = (rr & 15) * 64;
  const int bc = (rr >> 4) * 64;

  const float* xb = x + ((size_t)b * CC + bc) * NN + bn;
  __hip_bfloat16* xbo = xbf + ((size_t)b * CC + bc) * NN + bn;
  const int r0 = t >> 4;
  const int c0 = (t & 15) * 4;
  for (int p = 0; p < 4; ++p) {
    const int rw = r0 + p * 16;
    float4 v = *(const float4*)(xb + (size_t)rw * NN + c0);
    tile[rw][c0 + 0] = v.x;
    tile[rw][c0 + 1] = v.y;
    tile[rw][c0 + 2] = v.z;
    tile[rw][c0 + 3] = v.w;
    alignas(8) __hip_bfloat16 tm[4];
    tm[0] = __float2bfloat16(v.x);
    tm[1] = __float2bfloat16(v.y);
    tm[2] = __float2bfloat16(v.z);
    tm[3] = __float2bfloat16(v.w);
    *(bf16x4*)(xbo + (size_t)rw * NN + c0) = *(const bf16x4*)tm;
  }
  __syncthreads();

  __hip_bfloat16* xo = xT + ((size_t)b * NN + bn) * CC + bc;
  const int rn0 = t >> 3;
  const int cc0 = (t & 7) * 8;
  for (int p = 0; p < 2; ++p) {
    const int rn = rn0 + p * 32;
    alignas(16) __hip_bfloat16 tmp[8];
    for (int j = 0; j < 8; ++j) tmp[j] = __float2bfloat16(tile[cc0 + j][rn]);
    *(bf16x8*)(xo + (size_t)rn * CC + cc0) = *(const bf16x8*)tmp;
  }
}

// ------------------------------------------ fused QKV GEMM (W rows 0..1535 = q,k,v)
// r4-persistent engine (measured best: ~43us, WRITE at ideal 49.5MB). PLATEAU
// DECLARED (r9): 7 structures all land 585-607 TF = the m233 2-phase ceiling.
// FROZEN — do not touch.
__global__ __launch_bounds__(256, 2) void k_gemm_qkv(
    const __hip_bfloat16* __restrict__ Wqkv,
    const __hip_bfloat16* __restrict__ Xt,
    const float* __restrict__ bq, const float* __restrict__ bk,
    const float* __restrict__ bv,
    __hip_bfloat16* __restrict__ qT, __hip_bfloat16* __restrict__ kT,
    __hip_bfloat16* __restrict__ vO, float qscale) {
  __shared__ __hip_bfloat16 Wl[2][8192];   // [128 rows][64 cols] per buffer
  __shared__ __hip_bfloat16 Xl[2][8192];
  const int bid = blockIdx.x;               // 0..511
  const int by0 = bid >> 7;                 // 0..3   (rep r handles by0 + 4r)
  const int bx  = bid & 127;                // 0..127
  const int nt  = bx * 128;                 // global n = b*1024 + n
  const int bb  = nt >> 10;                 // batch (128-tiles never cross b)
  const int nb  = nt & 1023;
  const int t  = threadIdx.x;
  const int w  = t >> 6, l = t & 63;
  const int wr = w >> 1, wc = w & 1;
  const int lg = l >> 4, lr16 = l & 15;

  f32x4 acc[4][4] = {};

  const int srow = w * 8 + (l >> 3);
  const int scol = ((l & 7) ^ ((l >> 3) & 7)) * 8;   // pre-swizzled global col
  const __hip_bfloat16* wsrc0 = Wqkv + (size_t)(by0 * 128 + srow) * CC + scol;
  const __hip_bfloat16* xsrc  = Xt + ((size_t)nt + srow) * CC + scol;

  // 8 loads/lane per K-tile; A source re-based per rep (+512 rows per rep)
  auto STAGE = [&](int bn, int ktg) {
    const int rep = ktg >> 3;
    const int k0  = (ktg & 7) * 64;
    const __hip_bfloat16* ws = wsrc0 + (size_t)rep * 512 * CC;
#pragma unroll
    for (int i = 0; i < 4; ++i)
      glds16(ws + (size_t)(i * 32) * CC + k0, &Wl[bn][(w * 8 + i * 32) * 64]);
#pragma unroll
    for (int i = 0; i < 4; ++i)
      glds16(xsrc + (size_t)(i * 32) * CC + k0, &Xl[bn][(w * 8 + i * 32) * 64]);
  };

  const int s7 = lr16 & 7;
  const int slot0 = ((lg) ^ s7) * 8;
  const int slot1 = ((4 + lg) ^ s7) * 8;
  const int rowA = (wr * 64 + lr16) * 64;
  const int rowB = (wc * 64 + lr16) * 64;

  auto STEP = [&](int bn) {
    const __hip_bfloat16* Wb = &Wl[bn][0];
    const __hip_bfloat16* Xb = &Xl[bn][0];
#pragma unroll
    for (int ks = 0; ks < 2; ++ks) {
      const int sl = ks ? slot1 : slot0;
      bf16x8 af[4], bfr[4];
#pragma unroll
      for (int mi = 0; mi < 4; ++mi) af[mi] = *(const bf16x8*)(Wb + rowA + mi * 1024 + sl);
#pragma unroll
      for (int nj = 0; nj < 4; ++nj) bfr[nj] = *(const bf16x8*)(Xb + rowB + nj * 1024 + sl);
      __builtin_amdgcn_s_setprio(1);
#pragma unroll
      for (int mi = 0; mi < 4; ++mi)
#pragma unroll
        for (int nj = 0; nj < 4; ++nj)
          acc[mi][nj] = MFMA16(af[mi], bfr[nj], acc[mi][nj]);
      __builtin_amdgcn_s_setprio(0);
    }
  };

  STAGE(0, 0);
  STAGE(1, 1);
  for (int ktg = 0; ktg < 24; ++ktg) {
    if (ktg == 23)                    { WAITVM0;  }
    else if (ktg > 0 && (ktg & 7) == 0) { WAITVM16; }  // don't force store drain
    else                              { WAITVM8;  }
    BARRIER; SCHEDB;
    STEP(ktg & 1);
    BARRIER;
    if (ktg < 22) STAGE(ktg & 1, ktg + 2);

    if ((ktg & 7) == 7) {             // end of one output tile: epilogue
      const int rep = ktg >> 3;       // 0 Q, 1 K, 2 V
      const float* bias = (rep == 0) ? bq : (rep == 1) ? bk : bv;
      const float scale = (rep == 0) ? qscale : 1.0f;
      __hip_bfloat16* outT = (rep == 0) ? qT : kT;
#pragma unroll
      for (int mi = 0; mi < 4; ++mi) {
        const int o0 = by0 * 128 + wr * 64 + mi * 16 + lg * 4;   // 0..511
#pragma unroll
        for (int nj = 0; nj < 4; ++nj) {
          const int n = nb + wc * 64 + nj * 16 + lr16;
          if (rep < 2) {
            alignas(8) __hip_bfloat16 tmp[4];
#pragma unroll
            for (int rj = 0; rj < 4; ++rj)
              tmp[rj] = __float2bfloat16((acc[mi][nj][rj] + bias[o0 + rj]) * scale);
            const int hh = o0 >> 6, d0 = o0 & 63;
            *(bf16x4*)(outT + (((size_t)(bb * HH + hh)) * NN + n) * DD + d0) =
                *(const bf16x4*)tmp;
          } else {
#pragma unroll
            for (int rj = 0; rj < 4; ++rj)
              vO[((size_t)bb * CC + o0 + rj) * NN + n] =
                  __float2bfloat16(acc[mi][nj][rj] + bias[o0 + rj]);
          }
        }
      }
      if (ktg < 23) {
#pragma unroll
        for (int mi = 0; mi < 4; ++mi)
#pragma unroll
          for (int nj = 0; nj < 4; ++nj)
            acc[mi][nj] = f32x4{0.f, 0.f, 0.f, 0.f};
      }
    }
  }
}

// --------------------------------------------- output projection + residual GEMM
// Round-25: drop the trailing barrier (WAR-safe already: stage kt+2 targets
// buffer (kt-1)%3, whose reads happened before this iteration's LEADING
// barrier; ds_reads complete before the barrier since the compiler lgkm-waits
// before the MFMAs that precede it). 16 barriers/block instead of 32.
// 3-buffer + counted WAITVM4 ladder (r10), (256,4).
__global__ __launch_bounds__(256, 4) void k_gemm_o(
    const __hip_bfloat16* __restrict__ W,
    const __hip_bfloat16* __restrict__ Xt,
    const float* __restrict__ bias,
    const __hip_bfloat16* __restrict__ xbf,
    const float* __restrict__ gamma,
    float* __restrict__ y) {
  __shared__ __hip_bfloat16 Wl[3][4096];
  __shared__ __hip_bfloat16 Xl[3][4096];
  const int b  = blockIdx.z;
  const int ot = blockIdx.y * 128;
  const int nt = blockIdx.x * 128;
  const int t  = threadIdx.x;
  const int w  = t >> 6, l = t & 63;
  const int wr = w >> 1, wc = w & 1;
  const int lg = l >> 4, lr16 = l & 15;

  f32x4 acc[4][4] = {};

  const int srow = w * 16 + (l >> 2);
  const int scol = ((l & 3) ^ ((l >> 3) & 3)) * 8;
  const __hip_bfloat16* ws0 = W + (size_t)(ot + srow) * CC + scol;
  const __hip_bfloat16* xs0 = Xt + ((size_t)b * NN + nt + srow) * CC + scol;

  const int sx  = (lg ^ ((lr16 >> 1) & 3)) * 8;
  const int rdA = (wr * 64 + lr16) * 32 + sx;
  const int rdB = (wc * 64 + lr16) * 32 + sx;

#define STAGEO(bn, k0)                                        \
  do {                                                        \
    glds16(ws0 + (k0), &Wl[bn][w * 512]);                     \
    glds16(ws0 + (size_t)64 * CC + (k0), &Wl[bn][2048 + w * 512]); \
    glds16(xs0 + (k0), &Xl[bn][w * 512]);                     \
    glds16(xs0 + (size_t)64 * CC + (k0), &Xl[bn][2048 + w * 512]); \
  } while (0)

  STAGEO(0, 0);
  STAGEO(1, 32);
  for (int kt = 0; kt < 16; ++kt) {
    if (kt < 15) { WAITVM4; } else { WAITVM0; }
    BARRIER; SCHEDB;
    const __hip_bfloat16* Wb = &Wl[kt % 3][0];
    const __hip_bfloat16* Xb = &Xl[kt % 3][0];
    bf16x8 af[4], bfr[4];
#pragma unroll
    for (int mi = 0; mi < 4; ++mi) af[mi] = *(const bf16x8*)(Wb + rdA + mi * 512);
#pragma unroll
    for (int nj = 0; nj < 4; ++nj) bfr[nj] = *(const bf16x8*)(Xb + rdB + nj * 512);
    __builtin_amdgcn_s_setprio(1);
#pragma unroll
    for (int mi = 0; mi < 4; ++mi)
#pragma unroll
      for (int nj = 0; nj < 4; ++nj)
        acc[mi][nj] = MFMA16(af[mi], bfr[nj], acc[mi][nj]);
    __builtin_amdgcn_s_setprio(0);
    if (kt < 14) STAGEO((kt + 2) % 3, (kt + 2) * 32);
  }
#undef STAGEO

  const float g = gamma[0];
  for (int mi = 0; mi < 4; ++mi) {
    const int o0 = ot + wr * 64 + mi * 16 + lg * 4;
    for (int nj = 0; nj < 4; ++nj) {
      const int n = nt + wc * 64 + nj * 16 + lr16;
      for (int rj = 0; rj < 4; ++rj) {
        const size_t idx = ((size_t)b * CC + o0 + rj) * NN + n;
        y[idx] = g * (acc[mi][nj][rj] + bias[o0 + rj]) + __bfloat162float(xbf[idx]);
      }
    }
  }
}

// ---------------------------------------------------------------- attention core
// Round-25: 4-buffer K/V rotation (64KB LDS, still 2 blk/CU) -> ONE barrier per
// granule (was 2). Stage granule tl+3 into buffer (tl+3)&3, whose last read was
// iter tl-1 (V) / tl-2 (K) — separated by this iteration's leading barrier, so
// the trailing WAR barrier is gone (17 barriers vs 32). T15 pipeline unchanged:
// QK^T[tl+1] -> PV[tl] -> EXP[tl+1]. Ladder (own loads; visibility via
// WAIT->BARRIER order): tl<=13 VM4, tl=14 VM0, tl=15 none.
__global__ __launch_bounds__(256, 2) void k_attn(
    const __hip_bfloat16* __restrict__ qT,
    const __hip_bfloat16* __restrict__ kT,
    const __hip_bfloat16* __restrict__ v,
    __hip_bfloat16* __restrict__ attT) {
  __shared__ __hip_bfloat16 Kl[4][4096];
  __shared__ __hip_bfloat16 Vl[4][4096];

  const int L = blockIdx.x;                 // 512 blocks
  const int c = L & 7, s = L >> 3;
  const int bh = c * 16 + (s >> 2);
  const int i0 = (s & 3) * 256;
  const int b = bh >> 3, h = bh & 7;
  const int t  = threadIdx.x;
  const int w  = t >> 6, l = t & 63;
  const int lg = l >> 4, lr = l & 15;

  const __hip_bfloat16* qb = qT + ((size_t)(b * HH + h)) * NN * DD;
  const __hip_bfloat16* kb = kT + ((size_t)(b * HH + h)) * NN * DD;
  const __hip_bfloat16* vb = v + ((size_t)b * CC + h * DD) * NN;

  bf16x8 qf[4][2];
#pragma unroll
  for (int g = 0; g < 4; ++g) {
    const __hip_bfloat16* qp = qb + (size_t)(i0 + w * 64 + g * 16 + lr) * DD + lg * 8;
    qf[g][0] = *(const bf16x8*)qp;
    qf[g][1] = *(const bf16x8*)(qp + 32);
  }

  const int rA = w * 8 + (l >> 3);
  const int rB = rA + 32;
  const int sA = (l & 7) ^ ((rA & 3) ^ (((rA >> 3) & 1) << 2));
  const __hip_bfloat16* gKA = kb + rA * DD + sA * 8;
  const __hip_bfloat16* gKB = kb + rB * DD + sA * 8;
  const __hip_bfloat16* gVA = vb + (size_t)rA * NN + sA * 8;
  const __hip_bfloat16* gVB = vb + (size_t)rB * NN + sA * 8;

  auto STAGE = [&](int bufn, int tile) {
    glds16(gKA + (size_t)tile * 4096, &Kl[bufn][w * 512]);
    glds16(gKB + (size_t)tile * 4096, &Kl[bufn][2048 + w * 512]);
    glds16(gVA + tile * 64, &Vl[bufn][w * 512]);
    glds16(gVB + tile * 64, &Vl[bufn][2048 + w * 512]);
  };

  const int swzK = (lr & 3) ^ (((lr >> 2) & 1) << 2);
  const int krl  = 8 * (lr >> 2) + (lr & 3);
  const int offK0 = krl * 64 + ((lg ^ swzK) * 8);
  const int offK1 = krl * 64 + (((lg + 4) ^ swzK) * 8);
  const int swzV = (lr & 3) ^ (((lr >> 3) & 1) << 2);

  f32x4 accO[4][4] = {};
  f32x4 accL[4] = {};
  f32x4 st[4][4];
  bf16x8 pf[4][2];
  const bf16x8 ones = {(__bf16)1.f, (__bf16)1.f, (__bf16)1.f, (__bf16)1.f,
                       (__bf16)1.f, (__bf16)1.f, (__bf16)1.f, (__bf16)1.f};

  auto QK = [&](const __hip_bfloat16* Kb) {
    __builtin_amdgcn_s_setprio(1);
#pragma unroll
    for (int jt = 0; jt < 4; ++jt) {
      const int jo = (jt >> 1) * 2048 + (jt & 1) * 256;
      bf16x8 kf0 = *(const bf16x8*)(Kb + jo + offK0);
      bf16x8 kf1 = *(const bf16x8*)(Kb + jo + offK1);
#pragma unroll
      for (int g = 0; g < 4; ++g) {
        f32x4 a = {};
        a = MFMA16(kf0, qf[g][0], a);
        a = MFMA16(kf1, qf[g][1], a);
        st[g][jt] = a;
      }
    }
    __builtin_amdgcn_s_setprio(0);
  };

  auto EXP = [&]() {
#pragma unroll
    for (int g = 0; g < 4; ++g) {
      union { bf16x8 v8; __hip_bfloat16 h[8]; } pk0, pk1;
#pragma unroll
      for (int jt = 0; jt < 4; ++jt)
#pragma unroll
        for (int rj = 0; rj < 4; ++rj) {
          const float p = __builtin_amdgcn_exp2f(st[g][jt][rj]);
          if (jt < 2) pk0.h[(jt & 1) * 4 + rj] = __float2bfloat16(p);
          else        pk1.h[(jt & 1) * 4 + rj] = __float2bfloat16(p);
        }
      pf[g][0] = pk0.v8;
      pf[g][1] = pk1.v8;
    }
  };

  auto PV = [&](const __hip_bfloat16* Vb) {
    __builtin_amdgcn_s_setprio(1);
#pragma unroll
    for (int ks = 0; ks < 2; ++ks) {
#pragma unroll
      for (int dt = 0; dt < 4; ++dt) {
        bf16x8 vf = *(const bf16x8*)(Vb + (dt * 16 + lr) * 64 + (((ks * 4 + lg) ^ swzV) * 8));
#pragma unroll
        for (int g = 0; g < 4; ++g)
          accO[g][dt] = MFMA16(pf[g][ks], vf, accO[g][dt]);
      }
#pragma unroll
      for (int g = 0; g < 4; ++g)
        accL[g] = MFMA16(pf[g][ks], ones, accL[g]);
    }
    __builtin_amdgcn_s_setprio(0);
  };

  STAGE(0, 0);
  STAGE(1, 1);
  STAGE(2, 2);
  WAITVM8;                 // tile0 complete (tiles 1,2 = 8 loads in flight)
  BARRIER;
  QK(&Kl[0][0]);           // st = scores(tile0)
  EXP();                   // pf = P(tile0)

  for (int tl = 0; tl < 16; ++tl) {
    const int cur = tl & 3;
    if (tl < 15) {
      if (tl <= 13) { WAITVM4; } else { WAITVM0; }
      BARRIER; SCHEDB;
      QK(&Kl[(tl + 1) & 3][0]);   // st = scores(tl+1), indep of pf
      PV(&Vl[cur][0]);            // consumes pf = P(tl)
      EXP();                      // pf = P(tl+1); VALU overlaps PV drain
      if (tl < 13) STAGE((tl + 3) & 3, tl + 3);  // buffer last read iter tl-1
    } else {
      PV(&Vl[cur][0]);            // final tile
    }
  }

#pragma unroll
  for (int g = 0; g < 4; ++g)
#pragma unroll
    for (int dt = 0; dt < 4; ++dt) {
      f32x4 o;
#pragma unroll
      for (int rj = 0; rj < 4; ++rj) o[rj] = accO[g][dt][rj] / accL[g][rj];
#pragma unroll
      for (int rj = 0; rj < 4; ++rj) {
        const int i = i0 + w * 64 + g * 16 + 4 * lg + rj;
        const int d = dt * 16 + lr;
        attT[((size_t)b * NN + i) * CC + h * DD + d] = __float2bfloat16(o[rj]);
      }
    }
}

// ----------------------------------------------------------------------------
extern "C" void kernel_launch(void* const* d_in, const int* in_sizes, int n_in,
                              void* d_out, int out_size, void* d_ws, size_t ws_size,
                              hipStream_t stream) {
  const float* x     = (const float*)d_in[0];
  const float* wq    = (const float*)d_in[1];
  const float* bq    = (const float*)d_in[2];
  const float* wk    = (const float*)d_in[3];
  const float* bk    = (const float*)d_in[4];
  const float* wv    = (const float*)d_in[5];
  const float* bv    = (const float*)d_in[6];
  const float* wo    = (const float*)d_in[7];
  const float* bo    = (const float*)d_in[8];
  const float* gamma = (const float*)d_in[9];
  float* y = (float*)d_out;

  char* ws = (char*)d_ws;
  const size_t szT = (size_t)BB * NN * CC * 2;
  __hip_bfloat16* xT  = (__hip_bfloat16*)(ws);            // attn overwrites as attT
  __hip_bfloat16* qT  = (__hip_bfloat16*)(ws + szT);
  __hip_bfloat16* kTb = (__hip_bfloat16*)(ws + 2 * szT);
  __hip_bfloat16* vB  = (__hip_bfloat16*)(ws + 3 * szT);
  __hip_bfloat16* xbf = (__hip_bfloat16*)(ws + 4 * szT);  // bf16 [b][c][n] copy of x
  __hip_bfloat16* wqb = (__hip_bfloat16*)(ws + 5 * szT);  // wq,wk,wv,wo contiguous
  __hip_bfloat16* wob = wqb + (size_t)3 * CC * CC;

  k_prep<<<dim3(2048 + 1024), 256, 0, stream>>>(x, xT, xbf, wq, wk, wv, wo, wqb);

  // Q pre-scaled by SCALE * log2(e) so attention uses exp2 directly.
  const float qsc = 0.125f * 1.44269504f;
  k_gemm_qkv<<<dim3(512), 256, 0, stream>>>(
      wqb, xT, bq, bk, bv, qT, kTb, vB, qsc);

  // attn writes attT over the (now dead) xT buffer
  k_attn<<<dim3(BB * HH * (NN / 256)), 256, 0, stream>>>(qT, kTb, vB, xT);

  k_gemm_o<<<dim3(NN / 128, CC / 128, BB), 256, 0, stream>>>(
      wob, xT, bo, xbf, gamma, y);
}

// Round 12
// 106.495 us; speedup vs baseline: 1.0508x; 1.0174x over previous
//
#include <hip/hip_runtime.h>
#include <hip/hip_bf16.h>

#define BB 16
#define CC 512
#define HH 8
#define DD 64
#define NN 1024

using f32x4  = __attribute__((ext_vector_type(4))) float;
typedef __bf16 bf16x8 __attribute__((ext_vector_type(8)));
typedef __bf16 bf16x4 __attribute__((ext_vector_type(4)));

#define MFMA16(a, b, c) __builtin_amdgcn_mfma_f32_16x16x32_bf16((a), (b), (c), 0, 0, 0)

#define WAITVM16 asm volatile("s_waitcnt vmcnt(16)" ::: "memory")
#define WAITVM8  asm volatile("s_waitcnt vmcnt(8)" ::: "memory")
#define WAITVM4  asm volatile("s_waitcnt vmcnt(4)" ::: "memory")
#define WAITVM0  asm volatile("s_waitcnt vmcnt(0)" ::: "memory")
#define BARRIER __builtin_amdgcn_s_barrier()
#define SCHEDB  __builtin_amdgcn_sched_barrier(0)

// async global->LDS, 16B per lane. LDS dest must be wave-uniform base (+lane*16);
// the GLOBAL source address is per-lane (enables pre-swizzled staging).
__device__ __forceinline__ void glds16(const __hip_bfloat16* g, __hip_bfloat16* l) {
  typedef __attribute__((address_space(1))) const void gv_t;
  typedef __attribute__((address_space(3))) void lv_t;
  __builtin_amdgcn_global_load_lds((gv_t*)g, (lv_t*)l, 16, 0, 0);
}

// -------------------------- prep: x transpose->bf16 (blocks 0..2047) + 4 weight
// cvts (blocks 2048..3071). x-tile branch ALSO writes xbf, a bf16 [b][c][n] copy
// of x — gemm_o's residual reads 16MB bf16 instead of 64MB fp32.
// At memory floor (~73MB total traffic). Do not touch.
__global__ __launch_bounds__(256) void k_prep(
    const float* __restrict__ x, __hip_bfloat16* __restrict__ xT,
    __hip_bfloat16* __restrict__ xbf,
    const float* __restrict__ wq, const float* __restrict__ wk,
    const float* __restrict__ wv, const float* __restrict__ wo,
    __hip_bfloat16* __restrict__ wqb) {
  __shared__ float tile[64][65];
  const int L = blockIdx.x;
  const int t = threadIdx.x;
  if (L >= 2048) {
    const int j = L - 2048;
    const int mat = j >> 8;
    const float* s = (mat == 0) ? wq : (mat == 1) ? wk : (mat == 2) ? wv : wo;
    __hip_bfloat16* o = wqb + (size_t)mat * CC * CC;
    const int i = ((j & 255) * 256 + t) * 4;
    float4 v = *(const float4*)(s + i);
    alignas(8) __hip_bfloat16 tm[4];
    tm[0] = __float2bfloat16(v.x);
    tm[1] = __float2bfloat16(v.y);
    tm[2] = __float2bfloat16(v.z);
    tm[3] = __float2bfloat16(v.w);
    *(bf16x4*)(o + i) = *(const bf16x4*)tm;
    return;
  }
  const int c = L & 7, r = L >> 3;
  const int b  = c * 2 + (r >> 7);
  const int rr = r & 127;
  const int bn = (rr & 15) * 64;
  const int bc = (rr >> 4) * 64;

  const float* xb = x + ((size_t)b * CC + bc) * NN + bn;
  __hip_bfloat16* xbo = xbf + ((size_t)b * CC + bc) * NN + bn;
  const int r0 = t >> 4;
  const int c0 = (t & 15) * 4;
  for (int p = 0; p < 4; ++p) {
    const int rw = r0 + p * 16;
    float4 v = *(const float4*)(xb + (size_t)rw * NN + c0);
    tile[rw][c0 + 0] = v.x;
    tile[rw][c0 + 1] = v.y;
    tile[rw][c0 + 2] = v.z;
    tile[rw][c0 + 3] = v.w;
    alignas(8) __hip_bfloat16 tm[4];
    tm[0] = __float2bfloat16(v.x);
    tm[1] = __float2bfloat16(v.y);
    tm[2] = __float2bfloat16(v.z);
    tm[3] = __float2bfloat16(v.w);
    *(bf16x4*)(xbo + (size_t)rw * NN + c0) = *(const bf16x4*)tm;
  }
  __syncthreads();

  __hip_bfloat16* xo = xT + ((size_t)b * NN + bn) * CC + bc;
  const int rn0 = t >> 3;
  const int cc0 = (t & 7) * 8;
  for (int p = 0; p < 2; ++p) {
    const int rn = rn0 + p * 32;
    alignas(16) __hip_bfloat16 tmp[8];
    for (int j = 0; j < 8; ++j) tmp[j] = __float2bfloat16(tile[cc0 + j][rn]);
    *(bf16x8*)(xo + (size_t)rn * CC + cc0) = *(const bf16x8*)tmp;
  }
}

// ------------------------------------------ fused QKV GEMM (W rows 0..1535 = q,k,v)
// r4-persistent engine (measured best: ~43us, WRITE at ideal 49.5MB). PLATEAU
// DECLARED (r9): 7 structures all land 585-607 TF = the m233 2-phase ceiling.
// FROZEN — do not touch.
__global__ __launch_bounds__(256, 2) void k_gemm_qkv(
    const __hip_bfloat16* __restrict__ Wqkv,
    const __hip_bfloat16* __restrict__ Xt,
    const float* __restrict__ bq, const float* __restrict__ bk,
    const float* __restrict__ bv,
    __hip_bfloat16* __restrict__ qT, __hip_bfloat16* __restrict__ kT,
    __hip_bfloat16* __restrict__ vO, float qscale) {
  __shared__ __hip_bfloat16 Wl[2][8192];   // [128 rows][64 cols] per buffer
  __shared__ __hip_bfloat16 Xl[2][8192];
  const int bid = blockIdx.x;               // 0..511
  const int by0 = bid >> 7;                 // 0..3   (rep r handles by0 + 4r)
  const int bx  = bid & 127;                // 0..127
  const int nt  = bx * 128;                 // global n = b*1024 + n
  const int bb  = nt >> 10;                 // batch (128-tiles never cross b)
  const int nb  = nt & 1023;
  const int t  = threadIdx.x;
  const int w  = t >> 6, l = t & 63;
  const int wr = w >> 1, wc = w & 1;
  const int lg = l >> 4, lr16 = l & 15;

  f32x4 acc[4][4] = {};

  const int srow = w * 8 + (l >> 3);
  const int scol = ((l & 7) ^ ((l >> 3) & 7)) * 8;   // pre-swizzled global col
  const __hip_bfloat16* wsrc0 = Wqkv + (size_t)(by0 * 128 + srow) * CC + scol;
  const __hip_bfloat16* xsrc  = Xt + ((size_t)nt + srow) * CC + scol;

  // 8 loads/lane per K-tile; A source re-based per rep (+512 rows per rep)
  auto STAGE = [&](int bn, int ktg) {
    const int rep = ktg >> 3;
    const int k0  = (ktg & 7) * 64;
    const __hip_bfloat16* ws = wsrc0 + (size_t)rep * 512 * CC;
#pragma unroll
    for (int i = 0; i < 4; ++i)
      glds16(ws + (size_t)(i * 32) * CC + k0, &Wl[bn][(w * 8 + i * 32) * 64]);
#pragma unroll
    for (int i = 0; i < 4; ++i)
      glds16(xsrc + (size_t)(i * 32) * CC + k0, &Xl[bn][(w * 8 + i * 32) * 64]);
  };

  const int s7 = lr16 & 7;
  const int slot0 = ((lg) ^ s7) * 8;
  const int slot1 = ((4 + lg) ^ s7) * 8;
  const int rowA = (wr * 64 + lr16) * 64;
  const int rowB = (wc * 64 + lr16) * 64;

  auto STEP = [&](int bn) {
    const __hip_bfloat16* Wb = &Wl[bn][0];
    const __hip_bfloat16* Xb = &Xl[bn][0];
#pragma unroll
    for (int ks = 0; ks < 2; ++ks) {
      const int sl = ks ? slot1 : slot0;
      bf16x8 af[4], bfr[4];
#pragma unroll
      for (int mi = 0; mi < 4; ++mi) af[mi] = *(const bf16x8*)(Wb + rowA + mi * 1024 + sl);
#pragma unroll
      for (int nj = 0; nj < 4; ++nj) bfr[nj] = *(const bf16x8*)(Xb + rowB + nj * 1024 + sl);
      __builtin_amdgcn_s_setprio(1);
#pragma unroll
      for (int mi = 0; mi < 4; ++mi)
#pragma unroll
        for (int nj = 0; nj < 4; ++nj)
          acc[mi][nj] = MFMA16(af[mi], bfr[nj], acc[mi][nj]);
      __builtin_amdgcn_s_setprio(0);
    }
  };

  STAGE(0, 0);
  STAGE(1, 1);
  for (int ktg = 0; ktg < 24; ++ktg) {
    if (ktg == 23)                    { WAITVM0;  }
    else if (ktg > 0 && (ktg & 7) == 0) { WAITVM16; }  // don't force store drain
    else                              { WAITVM8;  }
    BARRIER; SCHEDB;
    STEP(ktg & 1);
    BARRIER;
    if (ktg < 22) STAGE(ktg & 1, ktg + 2);

    if ((ktg & 7) == 7) {             // end of one output tile: epilogue
      const int rep = ktg >> 3;       // 0 Q, 1 K, 2 V
      const float* bias = (rep == 0) ? bq : (rep == 1) ? bk : bv;
      const float scale = (rep == 0) ? qscale : 1.0f;
      __hip_bfloat16* outT = (rep == 0) ? qT : kT;
#pragma unroll
      for (int mi = 0; mi < 4; ++mi) {
        const int o0 = by0 * 128 + wr * 64 + mi * 16 + lg * 4;   // 0..511
#pragma unroll
        for (int nj = 0; nj < 4; ++nj) {
          const int n = nb + wc * 64 + nj * 16 + lr16;
          if (rep < 2) {
            alignas(8) __hip_bfloat16 tmp[4];
#pragma unroll
            for (int rj = 0; rj < 4; ++rj)
              tmp[rj] = __float2bfloat16((acc[mi][nj][rj] + bias[o0 + rj]) * scale);
            const int hh = o0 >> 6, d0 = o0 & 63;
            *(bf16x4*)(outT + (((size_t)(bb * HH + hh)) * NN + n) * DD + d0) =
                *(const bf16x4*)tmp;
          } else {
#pragma unroll
            for (int rj = 0; rj < 4; ++rj)
              vO[((size_t)bb * CC + o0 + rj) * NN + n] =
                  __float2bfloat16(acc[mi][nj][rj] + bias[o0 + rj]);
          }
        }
      }
      if (ktg < 23) {
#pragma unroll
        for (int mi = 0; mi < 4; ++mi)
#pragma unroll
          for (int nj = 0; nj < 4; ++nj)
            acc[mi][nj] = f32x4{0.f, 0.f, 0.f, 0.f};
      }
    }
  }
}

// --------------------------------------------- output projection + residual GEMM
// (r11 exact) 3-buffer, counted WAITVM4 ladder, single barrier per K-tile.
__global__ __launch_bounds__(256, 4) void k_gemm_o(
    const __hip_bfloat16* __restrict__ W,
    const __hip_bfloat16* __restrict__ Xt,
    const float* __restrict__ bias,
    const __hip_bfloat16* __restrict__ xbf,
    const float* __restrict__ gamma,
    float* __restrict__ y) {
  __shared__ __hip_bfloat16 Wl[3][4096];
  __shared__ __hip_bfloat16 Xl[3][4096];
  const int b  = blockIdx.z;
  const int ot = blockIdx.y * 128;
  const int nt = blockIdx.x * 128;
  const int t  = threadIdx.x;
  const int w  = t >> 6, l = t & 63;
  const int wr = w >> 1, wc = w & 1;
  const int lg = l >> 4, lr16 = l & 15;

  f32x4 acc[4][4] = {};

  const int srow = w * 16 + (l >> 2);
  const int scol = ((l & 3) ^ ((l >> 3) & 3)) * 8;
  const __hip_bfloat16* ws0 = W + (size_t)(ot + srow) * CC + scol;
  const __hip_bfloat16* xs0 = Xt + ((size_t)b * NN + nt + srow) * CC + scol;

  const int sx  = (lg ^ ((lr16 >> 1) & 3)) * 8;
  const int rdA = (wr * 64 + lr16) * 32 + sx;
  const int rdB = (wc * 64 + lr16) * 32 + sx;

#define STAGEO(bn, k0)                                        \
  do {                                                        \
    glds16(ws0 + (k0), &Wl[bn][w * 512]);                     \
    glds16(ws0 + (size_t)64 * CC + (k0), &Wl[bn][2048 + w * 512]); \
    glds16(xs0 + (k0), &Xl[bn][w * 512]);                     \
    glds16(xs0 + (size_t)64 * CC + (k0), &Xl[bn][2048 + w * 512]); \
  } while (0)

  STAGEO(0, 0);
  STAGEO(1, 32);
  for (int kt = 0; kt < 16; ++kt) {
    if (kt < 15) { WAITVM4; } else { WAITVM0; }
    BARRIER; SCHEDB;
    const __hip_bfloat16* Wb = &Wl[kt % 3][0];
    const __hip_bfloat16* Xb = &Xl[kt % 3][0];
    bf16x8 af[4], bfr[4];
#pragma unroll
    for (int mi = 0; mi < 4; ++mi) af[mi] = *(const bf16x8*)(Wb + rdA + mi * 512);
#pragma unroll
    for (int nj = 0; nj < 4; ++nj) bfr[nj] = *(const bf16x8*)(Xb + rdB + nj * 512);
    __builtin_amdgcn_s_setprio(1);
#pragma unroll
    for (int mi = 0; mi < 4; ++mi)
#pragma unroll
      for (int nj = 0; nj < 4; ++nj)
        acc[mi][nj] = MFMA16(af[mi], bfr[nj], acc[mi][nj]);
    __builtin_amdgcn_s_setprio(0);
    if (kt < 14) STAGEO((kt + 2) % 3, (kt + 2) * 32);
  }
#undef STAGEO

  const float g = gamma[0];
  for (int mi = 0; mi < 4; ++mi) {
    const int o0 = ot + wr * 64 + mi * 16 + lg * 4;
    for (int nj = 0; nj < 4; ++nj) {
      const int n = nt + wc * 64 + nj * 16 + lr16;
      for (int rj = 0; rj < 4; ++rj) {
        const size_t idx = ((size_t)b * CC + o0 + rj) * NN + n;
        y[idx] = g * (acc[mi][nj][rj] + bias[o0 + rj]) + __bfloat162float(xbf[idx]);
      }
    }
  }
}

// ---------------------------------------------------------------- attention core
// r11 structure (4-buffer single-barrier + T15 pipeline) + round-26 polish:
// epilogue divides (64 full-precision f32 divs ~10 insts each) replaced by 16
// v_rcp_f32 (one per (g,rj), reused across 4 dt) + 64 muls. Output rounds to
// bf16 (8-bit mantissa) so v_rcp's ~2^-22 rel error is far below the rounding.
__global__ __launch_bounds__(256, 2) void k_attn(
    const __hip_bfloat16* __restrict__ qT,
    const __hip_bfloat16* __restrict__ kT,
    const __hip_bfloat16* __restrict__ v,
    __hip_bfloat16* __restrict__ attT) {
  __shared__ __hip_bfloat16 Kl[4][4096];
  __shared__ __hip_bfloat16 Vl[4][4096];

  const int L = blockIdx.x;                 // 512 blocks
  const int c = L & 7, s = L >> 3;
  const int bh = c * 16 + (s >> 2);
  const int i0 = (s & 3) * 256;
  const int b = bh >> 3, h = bh & 7;
  const int t  = threadIdx.x;
  const int w  = t >> 6, l = t & 63;
  const int lg = l >> 4, lr = l & 15;

  const __hip_bfloat16* qb = qT + ((size_t)(b * HH + h)) * NN * DD;
  const __hip_bfloat16* kb = kT + ((size_t)(b * HH + h)) * NN * DD;
  const __hip_bfloat16* vb = v + ((size_t)b * CC + h * DD) * NN;

  bf16x8 qf[4][2];
#pragma unroll
  for (int g = 0; g < 4; ++g) {
    const __hip_bfloat16* qp = qb + (size_t)(i0 + w * 64 + g * 16 + lr) * DD + lg * 8;
    qf[g][0] = *(const bf16x8*)qp;
    qf[g][1] = *(const bf16x8*)(qp + 32);
  }

  const int rA = w * 8 + (l >> 3);
  const int rB = rA + 32;
  const int sA = (l & 7) ^ ((rA & 3) ^ (((rA >> 3) & 1) << 2));
  const __hip_bfloat16* gKA = kb + rA * DD + sA * 8;
  const __hip_bfloat16* gKB = kb + rB * DD + sA * 8;
  const __hip_bfloat16* gVA = vb + (size_t)rA * NN + sA * 8;
  const __hip_bfloat16* gVB = vb + (size_t)rB * NN + sA * 8;

  auto STAGE = [&](int bufn, int tile) {
    glds16(gKA + (size_t)tile * 4096, &Kl[bufn][w * 512]);
    glds16(gKB + (size_t)tile * 4096, &Kl[bufn][2048 + w * 512]);
    glds16(gVA + tile * 64, &Vl[bufn][w * 512]);
    glds16(gVB + tile * 64, &Vl[bufn][2048 + w * 512]);
  };

  const int swzK = (lr & 3) ^ (((lr >> 2) & 1) << 2);
  const int krl  = 8 * (lr >> 2) + (lr & 3);
  const int offK0 = krl * 64 + ((lg ^ swzK) * 8);
  const int offK1 = krl * 64 + (((lg + 4) ^ swzK) * 8);
  const int swzV = (lr & 3) ^ (((lr >> 3) & 1) << 2);

  f32x4 accO[4][4] = {};
  f32x4 accL[4] = {};
  f32x4 st[4][4];
  bf16x8 pf[4][2];
  const bf16x8 ones = {(__bf16)1.f, (__bf16)1.f, (__bf16)1.f, (__bf16)1.f,
                       (__bf16)1.f, (__bf16)1.f, (__bf16)1.f, (__bf16)1.f};

  auto QK = [&](const __hip_bfloat16* Kb) {
    __builtin_amdgcn_s_setprio(1);
#pragma unroll
    for (int jt = 0; jt < 4; ++jt) {
      const int jo = (jt >> 1) * 2048 + (jt & 1) * 256;
      bf16x8 kf0 = *(const bf16x8*)(Kb + jo + offK0);
      bf16x8 kf1 = *(const bf16x8*)(Kb + jo + offK1);
#pragma unroll
      for (int g = 0; g < 4; ++g) {
        f32x4 a = {};
        a = MFMA16(kf0, qf[g][0], a);
        a = MFMA16(kf1, qf[g][1], a);
        st[g][jt] = a;
      }
    }
    __builtin_amdgcn_s_setprio(0);
  };

  auto EXP = [&]() {
#pragma unroll
    for (int g = 0; g < 4; ++g) {
      union { bf16x8 v8; __hip_bfloat16 h[8]; } pk0, pk1;
#pragma unroll
      for (int jt = 0; jt < 4; ++jt)
#pragma unroll
        for (int rj = 0; rj < 4; ++rj) {
          const float p = __builtin_amdgcn_exp2f(st[g][jt][rj]);
          if (jt < 2) pk0.h[(jt & 1) * 4 + rj] = __float2bfloat16(p);
          else        pk1.h[(jt & 1) * 4 + rj] = __float2bfloat16(p);
        }
      pf[g][0] = pk0.v8;
      pf[g][1] = pk1.v8;
    }
  };

  auto PV = [&](const __hip_bfloat16* Vb) {
    __builtin_amdgcn_s_setprio(1);
#pragma unroll
    for (int ks = 0; ks < 2; ++ks) {
#pragma unroll
      for (int dt = 0; dt < 4; ++dt) {
        bf16x8 vf = *(const bf16x8*)(Vb + (dt * 16 + lr) * 64 + (((ks * 4 + lg) ^ swzV) * 8));
#pragma unroll
        for (int g = 0; g < 4; ++g)
          accO[g][dt] = MFMA16(pf[g][ks], vf, accO[g][dt]);
      }
#pragma unroll
      for (int g = 0; g < 4; ++g)
        accL[g] = MFMA16(pf[g][ks], ones, accL[g]);
    }
    __builtin_amdgcn_s_setprio(0);
  };

  STAGE(0, 0);
  STAGE(1, 1);
  STAGE(2, 2);
  WAITVM8;                 // tile0 complete (tiles 1,2 = 8 loads in flight)
  BARRIER;
  QK(&Kl[0][0]);           // st = scores(tile0)
  EXP();                   // pf = P(tile0)

  for (int tl = 0; tl < 16; ++tl) {
    const int cur = tl & 3;
    if (tl < 15) {
      if (tl <= 13) { WAITVM4; } else { WAITVM0; }
      BARRIER; SCHEDB;
      QK(&Kl[(tl + 1) & 3][0]);   // st = scores(tl+1), indep of pf
      PV(&Vl[cur][0]);            // consumes pf = P(tl)
      EXP();                      // pf = P(tl+1); VALU overlaps PV drain
      if (tl < 13) STAGE((tl + 3) & 3, tl + 3);  // buffer last read iter tl-1
    } else {
      PV(&Vl[cur][0]);            // final tile
    }
  }

#pragma unroll
  for (int g = 0; g < 4; ++g) {
    f32x4 rc;
#pragma unroll
    for (int rj = 0; rj < 4; ++rj) {
      float r;
      asm("v_rcp_f32 %0, %1" : "=v"(r) : "v"(accL[g][rj]));
      rc[rj] = r;
    }
#pragma unroll
    for (int dt = 0; dt < 4; ++dt) {
      f32x4 o;
#pragma unroll
      for (int rj = 0; rj < 4; ++rj) o[rj] = accO[g][dt][rj] * rc[rj];
#pragma unroll
      for (int rj = 0; rj < 4; ++rj) {
        const int i = i0 + w * 64 + g * 16 + 4 * lg + rj;
        const int d = dt * 16 + lr;
        attT[((size_t)b * NN + i) * CC + h * DD + d] = __float2bfloat16(o[rj]);
      }
    }
  }
}

// ----------------------------------------------------------------------------
extern "C" void kernel_launch(void* const* d_in, const int* in_sizes, int n_in,
                              void* d_out, int out_size, void* d_ws, size_t ws_size,
                              hipStream_t stream) {
  const float* x     = (const float*)d_in[0];
  const float* wq    = (const float*)d_in[1];
  const float* bq    = (const float*)d_in[2];
  const float* wk    = (const float*)d_in[3];
  const float* bk    = (const float*)d_in[4];
  const float* wv    = (const float*)d_in[5];
  const float* bv    = (const float*)d_in[6];
  const float* wo    = (const float*)d_in[7];
  const float* bo    = (const float*)d_in[8];
  const float* gamma = (const float*)d_in[9];
  float* y = (float*)d_out;

  char* ws = (char*)d_ws;
  const size_t szT = (size_t)BB * NN * CC * 2;
  __hip_bfloat16* xT  = (__hip_bfloat16*)(ws);            // attn overwrites as attT
  __hip_bfloat16* qT  = (__hip_bfloat16*)(ws + szT);
  __hip_bfloat16* kTb = (__hip_bfloat16*)(ws + 2 * szT);
  __hip_bfloat16* vB  = (__hip_bfloat16*)(ws + 3 * szT);
  __hip_bfloat16* xbf = (__hip_bfloat16*)(ws + 4 * szT);  // bf16 [b][c][n] copy of x
  __hip_bfloat16* wqb = (__hip_bfloat16*)(ws + 5 * szT);  // wq,wk,wv,wo contiguous
  __hip_bfloat16* wob = wqb + (size_t)3 * CC * CC;

  k_prep<<<dim3(2048 + 1024), 256, 0, stream>>>(x, xT, xbf, wq, wk, wv, wo, wqb);

  // Q pre-scaled by SCALE * log2(e) so attention uses exp2 directly.
  const float qsc = 0.125f * 1.44269504f;
  k_gemm_qkv<<<dim3(512), 256, 0, stream>>>(
      wqb, xT, bq, bk, bv, qT, kTb, vB, qsc);

  // attn writes attT over the (now dead) xT buffer
  k_attn<<<dim3(BB * HH * (NN / 256)), 256, 0, stream>>>(qT, kTb, vB, xT);

  k_gemm_o<<<dim3(NN / 128, CC / 128, BB), 256, 0, stream>>>(
      wob, xT, bo, xbf, gamma, y);
}